// Round 2
// baseline (235.139 us; speedup 1.0000x reference)
//
#include <hip/hip_runtime.h>
#include <math.h>

#define NHEADS 8
#define DHEAD 64
#define NDIM 512
#define NFREQ 32
#define POSD 130           // 2*(32*2+1)
#define NB 2
#define NL 272
#define NLS 256
#define NROWS (NB*NL)      // 544
#define NSPLIT 4
#define PART_STRIDE 528    // 512 out + 8 m + 8 l
#define ATTN_SCALE 0.125f
#define PHYS_SCALE 51.5f
#define PI_F 3.14159265358979323846f

// ---------------------------------------------------------------------------
// K1: qkv = x @ [Wq | Wk[:512] | Wv[:512]]   (M=544, N=1536, K=512, fp32)
// ---------------------------------------------------------------------------
__global__ __launch_bounds__(256) void qkv_gemm_k(
    const float* __restrict__ x,
    const float* __restrict__ Wq, const float* __restrict__ Wk,
    const float* __restrict__ Wv,
    float* __restrict__ qkv)
{
  __shared__ float As[16][68];
  __shared__ float Bs[16][64];
  const int t  = threadIdx.x;
  const int m0 = blockIdx.x * 64;
  const int ng = blockIdx.y * 64;
  const int region = ng >> 9;
  const int n0 = ng & 511;
  const float* W = (region == 0) ? Wq : (region == 1) ? Wk : Wv;
  float* out = qkv + (size_t)region * (NROWS * NDIM);

  const int tx = t & 15, ty = t >> 4;
  const int arow = t >> 2, akq = (t & 3) * 4;
  const int brow = t >> 4, bcol = (t & 15) * 4;

  float acc[4][4];
#pragma unroll
  for (int i = 0; i < 4; ++i)
#pragma unroll
    for (int j = 0; j < 4; ++j) acc[i][j] = 0.f;

  for (int k0 = 0; k0 < 512; k0 += 16) {
    float4 av = make_float4(0.f, 0.f, 0.f, 0.f);
    if (m0 + arow < NROWS)
      av = *(const float4*)&x[(size_t)(m0 + arow) * NDIM + k0 + akq];
    As[akq + 0][arow] = av.x; As[akq + 1][arow] = av.y;
    As[akq + 2][arow] = av.z; As[akq + 3][arow] = av.w;
    *(float4*)&Bs[brow][bcol] =
        *(const float4*)&W[(size_t)(k0 + brow) * NDIM + n0 + bcol];
    __syncthreads();
#pragma unroll
    for (int kk = 0; kk < 16; ++kk) {
      float4 a = *(const float4*)&As[kk][ty * 4];
      float4 b = *(const float4*)&Bs[kk][tx * 4];
      float aa[4] = {a.x, a.y, a.z, a.w};
      float bb[4] = {b.x, b.y, b.z, b.w};
#pragma unroll
      for (int i = 0; i < 4; ++i)
#pragma unroll
        for (int j = 0; j < 4; ++j) acc[i][j] = fmaf(aa[i], bb[j], acc[i][j]);
    }
    __syncthreads();
  }
#pragma unroll
  for (int i = 0; i < 4; ++i) {
    int row = m0 + ty * 4 + i;
    if (row < NROWS)
      *(float4*)&out[(size_t)row * NDIM + n0 + tx * 4] =
          make_float4(acc[i][0], acc[i][1], acc[i][2], acc[i][3]);
  }
}

// ---------------------------------------------------------------------------
// K4: out = attn_out @ Wo + bo
// ---------------------------------------------------------------------------
__global__ __launch_bounds__(256) void out_gemm_k(
    const float* __restrict__ A, const float* __restrict__ Wo,
    const float* __restrict__ bo, float* __restrict__ out)
{
  __shared__ float As[16][68];
  __shared__ float Bs[16][64];
  const int t  = threadIdx.x;
  const int m0 = blockIdx.x * 64;
  const int n0 = blockIdx.y * 64;

  const int tx = t & 15, ty = t >> 4;
  const int arow = t >> 2, akq = (t & 3) * 4;
  const int brow = t >> 4, bcol = (t & 15) * 4;

  float acc[4][4];
#pragma unroll
  for (int i = 0; i < 4; ++i)
#pragma unroll
    for (int j = 0; j < 4; ++j) acc[i][j] = 0.f;

  for (int k0 = 0; k0 < 512; k0 += 16) {
    float4 av = make_float4(0.f, 0.f, 0.f, 0.f);
    if (m0 + arow < NROWS)
      av = *(const float4*)&A[(size_t)(m0 + arow) * NDIM + k0 + akq];
    As[akq + 0][arow] = av.x; As[akq + 1][arow] = av.y;
    As[akq + 2][arow] = av.z; As[akq + 3][arow] = av.w;
    *(float4*)&Bs[brow][bcol] =
        *(const float4*)&Wo[(size_t)(k0 + brow) * NDIM + n0 + bcol];
    __syncthreads();
#pragma unroll
    for (int kk = 0; kk < 16; ++kk) {
      float4 a = *(const float4*)&As[kk][ty * 4];
      float4 b = *(const float4*)&Bs[kk][tx * 4];
      float aa[4] = {a.x, a.y, a.z, a.w};
      float bb[4] = {b.x, b.y, b.z, b.w};
#pragma unroll
      for (int i = 0; i < 4; ++i)
#pragma unroll
        for (int j = 0; j < 4; ++j) acc[i][j] = fmaf(aa[i], bb[j], acc[i][j]);
    }
    __syncthreads();
  }
  float4 bv = *(const float4*)&bo[n0 + tx * 4];
  float bb[4] = {bv.x, bv.y, bv.z, bv.w};
#pragma unroll
  for (int i = 0; i < 4; ++i) {
    int row = m0 + ty * 4 + i;
    if (row < NROWS)
      *(float4*)&out[(size_t)row * NDIM + n0 + tx * 4] =
          make_float4(acc[i][0] + bb[0], acc[i][1] + bb[1],
                      acc[i][2] + bb[2], acc[i][3] + bb[3]);
  }
}

// ---------------------------------------------------------------------------
// K2: split-K attention. Block = (row, split). Split s handles keys
// [64s, 64s+64) in two 32-key subtiles; split 3 also does the 16 global keys.
// Writes unnormalized partial (out[512], m[8], l[8]) per (row, split).
// ---------------------------------------------------------------------------
__global__ __launch_bounds__(256) void attn_split_k(
    const float* __restrict__ qb, const float* __restrict__ kb,
    const float* __restrict__ vb, const float* __restrict__ pos,
    const float* __restrict__ Wk, const float* __restrict__ Wv,
    const float* __restrict__ freqs, float* __restrict__ part)
{
  __shared__ float pe_s[32 * 132];      // [j][f], row stride 132 (16B aligned)
  __shared__ float u_s[NHEADS * 132];   // q @ Wk_pe^T
  __shared__ float w_s[NHEADS * 132];
  __shared__ float q_s[NDIM];
  __shared__ float s_s[NHEADS][32];
  __shared__ float fr_s[NFREQ];
  __shared__ float m_s[NHEADS], l_s[NHEADS], fac_s[NHEADS];

  const int row = blockIdx.x;
  const int s   = blockIdx.y;
  const int b   = row / NL;
  const int i   = row - b * NL;
  const bool spatial = (i < NLS);
  const int t = threadIdx.x;

  if (t < NFREQ) fr_s[t] = freqs[t];
  {
    float2 qv = *(const float2*)&qb[(size_t)row * NDIM + t * 2];
    q_s[t * 2] = qv.x; q_s[t * 2 + 1] = qv.y;
  }
  if (t < NHEADS) { m_s[t] = -1e30f; l_s[t] = 0.f; }
  __syncthreads();

  // u[h][f] = sum_d q[h*64+d] * Wk[512+f][h*64+d]
  if (spatial) {
    for (int idx = t; idx < NHEADS * POSD; idx += 256) {
      int h = idx / POSD, f = idx - h * POSD;
      const float* wr = &Wk[(size_t)(512 + f) * NDIM + h * DHEAD];
      const float* qs = &q_s[h * DHEAD];
      float a0 = 0.f, a1 = 0.f;
#pragma unroll
      for (int d = 0; d < 64; d += 8) {
        float4 w0 = *(const float4*)&wr[d];
        float4 w1 = *(const float4*)&wr[d + 4];
        a0 = fmaf(qs[d], w0.x, a0);     a0 = fmaf(qs[d + 1], w0.y, a0);
        a0 = fmaf(qs[d + 2], w0.z, a0); a0 = fmaf(qs[d + 3], w0.w, a0);
        a1 = fmaf(qs[d + 4], w1.x, a1); a1 = fmaf(qs[d + 5], w1.y, a1);
        a1 = fmaf(qs[d + 6], w1.z, a1); a1 = fmaf(qs[d + 7], w1.w, a1);
      }
      u_s[h * 132 + f] = a0 + a1;
    }
  }

  float px = 0.f, py = 0.f;
  if (spatial) {
    float2 pv = *(const float2*)&pos[(size_t)(b * NLS + i) * 2];
    px = pv.x; py = pv.y;
  }

  const int h_o = t >> 5;
  const int d0  = (t & 31) * 2;
  const int qd  = t & 31;          // w f-quad index: f0 = 4*qd covers 0..127
  const int f0w = 4 * qd;
  const int ftail = (qd == 0) ? 64 + 64 : 129;  // dummy init; real below
  (void)ftail;
  float out0 = 0.f, out1 = 0.f;
  float w0 = 0.f, w1 = 0.f, w2 = 0.f, w3 = 0.f, wt = 0.f;

  for (int sub = 0; sub < 2; ++sub) {
    const int key0 = 64 * s + 32 * sub;     // always < 256
    const bool pe_act = spatial;

    __syncthreads();

    // ---- phase A: pe tile (32 keys), layout pe_s[j*132 + f] ----
    if (pe_act) {
      const int j = t >> 3;
      const int fq = (t & 7) * 4;
      float2 kp = *(const float2*)&pos[(size_t)(b * NLS + key0 + j) * 2];
      float dx = kp.x - px, dy = kp.y - py;
      float r = sqrtf(dx * dx + dy * dy + 1e-8f);
      float rc = r / (PHYS_SCALE + r);
      float thn = atan2f(dy, dx) * (1.0f / PI_F);
      float* pr = &pe_s[j * 132];
      if ((t & 7) == 0) { pr[64] = rc; pr[129] = thn; }
#pragma unroll
      for (int k = 0; k < 4; ++k) {
        int f = fq + k;
        float fr = fr_s[f];
        float s1, c1, s2, c2;
        __sincosf(rc * fr * PI_F, &s1, &c1);
        __sincosf(thn * fr * PI_F, &s2, &c2);
        pr[f] = s1; pr[32 + f] = c1; pr[65 + f] = s2; pr[97 + f] = c2;
      }
    }
    __syncthreads();

    // ---- phase B: logits (h = t>>5, j = t&31) ----
    {
      const int h = t >> 5, j = t & 31;
      const float* kr = &kb[(size_t)(b * NL + key0 + j) * NDIM + h * DHEAD];
      const float* qs = &q_s[h * DHEAD];
      float a0 = 0.f, a1 = 0.f;
#pragma unroll
      for (int d = 0; d < 64; d += 8) {
        float4 k0v = *(const float4*)&kr[d];
        float4 k1v = *(const float4*)&kr[d + 4];
        a0 = fmaf(qs[d], k0v.x, a0);     a0 = fmaf(qs[d + 1], k0v.y, a0);
        a0 = fmaf(qs[d + 2], k0v.z, a0); a0 = fmaf(qs[d + 3], k0v.w, a0);
        a1 = fmaf(qs[d + 4], k1v.x, a1); a1 = fmaf(qs[d + 5], k1v.y, a1);
        a1 = fmaf(qs[d + 6], k1v.z, a1); a1 = fmaf(qs[d + 7], k1v.w, a1);
      }
      if (pe_act) {
        const float* pr = &pe_s[j * 132];
        const float* uu = &u_s[h * 132];
#pragma unroll
        for (int f = 0; f < 128; f += 4) {
          float4 p4 = *(const float4*)&pr[f];
          float4 u4 = *(const float4*)&uu[f];
          a0 = fmaf(p4.x, u4.x, a0); a1 = fmaf(p4.y, u4.y, a1);
          a0 = fmaf(p4.z, u4.z, a0); a1 = fmaf(p4.w, u4.w, a1);
        }
        a0 = fmaf(pr[128], uu[128], a0);
        a1 = fmaf(pr[129], uu[129], a1);
      }
      s_s[h][j] = (a0 + a1) * ATTN_SCALE;
    }
    __syncthreads();

    // ---- phase C: online softmax (32 lanes per head) ----
    {
      const int h = t >> 5, lane = t & 31;
      float v = s_s[h][lane];
      float mx = v;
#pragma unroll
      for (int off = 16; off > 0; off >>= 1)
        mx = fmaxf(mx, __shfl_xor(mx, off, 32));
      float m_old = m_s[h];
      float m_new = fmaxf(m_old, mx);
      float p = __expf(v - m_new);
      s_s[h][lane] = p;
      float sum = p;
#pragma unroll
      for (int off = 16; off > 0; off >>= 1)
        sum += __shfl_xor(sum, off, 32);
      if (lane == 0) {
        float fac = __expf(m_old - m_new);
        m_s[h] = m_new;
        l_s[h] = l_s[h] * fac + sum;
        fac_s[h] = fac;
      }
    }
    __syncthreads();

    // ---- phase D: PV ----
    {
      float fac = fac_s[h_o];
      out0 *= fac; out1 *= fac;
      const float* vbase = &vb[(size_t)(b * NL + key0) * NDIM + h_o * DHEAD + d0];
      const float* pp = s_s[h_o];
#pragma unroll 4
      for (int j = 0; j < 32; ++j) {
        float p = pp[j];
        float2 vv = *(const float2*)&vbase[(size_t)j * NDIM];
        out0 = fmaf(p, vv.x, out0);
        out1 = fmaf(p, vv.y, out1);
      }
    }
    // ---- phase E: w accumulate ----
    if (spatial) {
      const int h = h_o;
      float fac = fac_s[h];
      w0 *= fac; w1 *= fac; w2 *= fac; w3 *= fac; wt *= fac;
      const float* pp = s_s[h];
      const int ft = (qd == 0) ? 128 : 129;
#pragma unroll 4
      for (int j = 0; j < 32; ++j) {
        float p = pp[j];
        const float* pr = &pe_s[j * 132];
        float4 p4 = *(const float4*)&pr[f0w];
        w0 = fmaf(p, p4.x, w0); w1 = fmaf(p, p4.y, w1);
        w2 = fmaf(p, p4.z, w2); w3 = fmaf(p, p4.w, w3);
        if (qd < 2) wt = fmaf(p, pr[ft], wt);
      }
    }
  }

  // ---- split 3: 16 global keys, no pe ----
  if (s == 3) {
    const int key0 = 256;
    __syncthreads();
    {
      const int h = t >> 5, j = t & 31;
      if (j < 16) {
        const float* kr = &kb[(size_t)(b * NL + key0 + j) * NDIM + h * DHEAD];
        const float* qs = &q_s[h * DHEAD];
        float a0 = 0.f, a1 = 0.f;
#pragma unroll
        for (int d = 0; d < 64; d += 8) {
          float4 k0v = *(const float4*)&kr[d];
          float4 k1v = *(const float4*)&kr[d + 4];
          a0 = fmaf(qs[d], k0v.x, a0);     a0 = fmaf(qs[d + 1], k0v.y, a0);
          a0 = fmaf(qs[d + 2], k0v.z, a0); a0 = fmaf(qs[d + 3], k0v.w, a0);
          a1 = fmaf(qs[d + 4], k1v.x, a1); a1 = fmaf(qs[d + 5], k1v.y, a1);
          a1 = fmaf(qs[d + 6], k1v.z, a1); a1 = fmaf(qs[d + 7], k1v.w, a1);
        }
        s_s[h][j] = (a0 + a1) * ATTN_SCALE;
      }
    }
    __syncthreads();
    {
      const int h = t >> 5, lane = t & 31;
      float v = (lane < 16) ? s_s[h][lane] : -1e30f;
      float mx = v;
#pragma unroll
      for (int off = 16; off > 0; off >>= 1)
        mx = fmaxf(mx, __shfl_xor(mx, off, 32));
      float m_old = m_s[h];
      float m_new = fmaxf(m_old, mx);
      float p = (lane < 16) ? __expf(v - m_new) : 0.f;
      s_s[h][lane] = p;
      float sum = p;
#pragma unroll
      for (int off = 16; off > 0; off >>= 1)
        sum += __shfl_xor(sum, off, 32);
      if (lane == 0) {
        float fac = __expf(m_old - m_new);
        m_s[h] = m_new;
        l_s[h] = l_s[h] * fac + sum;
        fac_s[h] = fac;
      }
    }
    __syncthreads();
    {
      float fac = fac_s[h_o];
      out0 *= fac; out1 *= fac;
      const float* vbase = &vb[(size_t)(b * NL + key0) * NDIM + h_o * DHEAD + d0];
      const float* pp = s_s[h_o];
#pragma unroll 4
      for (int j = 0; j < 16; ++j) {
        float p = pp[j];
        float2 vv = *(const float2*)&vbase[(size_t)j * NDIM];
        out0 = fmaf(p, vv.x, out0);
        out1 = fmaf(p, vv.y, out1);
      }
      if (spatial) {
        w0 *= fac; w1 *= fac; w2 *= fac; w3 *= fac; wt *= fac;
      }
    }
  }

  // ---- epilogue: w @ Wv_pe projection, write partial ----
  __syncthreads();
  if (spatial) {
    float* wr = &w_s[h_o * 132];
    wr[f0w + 0] = w0; wr[f0w + 1] = w1; wr[f0w + 2] = w2; wr[f0w + 3] = w3;
    if (qd < 2) wr[(qd == 0) ? 128 : 129] = wt;
  }
  __syncthreads();
  if (spatial) {
    const float* wr = &w_s[h_o * 132];
    const float* wvb = &Wv[(size_t)512 * NDIM + h_o * DHEAD + d0];
#pragma unroll 8
    for (int f = 0; f < 128; f += 4) {
      float4 w4 = *(const float4*)&wr[f];
      float2 a0v = *(const float2*)&wvb[(size_t)(f + 0) * NDIM];
      float2 a1v = *(const float2*)&wvb[(size_t)(f + 1) * NDIM];
      float2 a2v = *(const float2*)&wvb[(size_t)(f + 2) * NDIM];
      float2 a3v = *(const float2*)&wvb[(size_t)(f + 3) * NDIM];
      out0 = fmaf(w4.x, a0v.x, out0); out1 = fmaf(w4.x, a0v.y, out1);
      out0 = fmaf(w4.y, a1v.x, out0); out1 = fmaf(w4.y, a1v.y, out1);
      out0 = fmaf(w4.z, a2v.x, out0); out1 = fmaf(w4.z, a2v.y, out1);
      out0 = fmaf(w4.w, a3v.x, out0); out1 = fmaf(w4.w, a3v.y, out1);
    }
    {
      float2 a0v = *(const float2*)&wvb[(size_t)128 * NDIM];
      float2 a1v = *(const float2*)&wvb[(size_t)129 * NDIM];
      out0 = fmaf(wr[128], a0v.x, out0); out1 = fmaf(wr[128], a0v.y, out1);
      out0 = fmaf(wr[129], a1v.x, out0); out1 = fmaf(wr[129], a1v.y, out1);
    }
  }

  float* prow = part + ((size_t)s * NROWS + row) * PART_STRIDE;
  *(float2*)&prow[h_o * DHEAD + d0] = make_float2(out0, out1);
  if (t < NHEADS) { prow[512 + t] = m_s[t]; prow[520 + t] = l_s[t]; }
}

// ---------------------------------------------------------------------------
// K3: combine split partials
// ---------------------------------------------------------------------------
__global__ __launch_bounds__(256) void combine_k(
    const float* __restrict__ part, float* __restrict__ ao)
{
  const int row = blockIdx.x;
  const int t = threadIdx.x;
  const int h_o = t >> 5;
  const int d0 = (t & 31) * 2;

  float m[NSPLIT], l[NSPLIT];
#pragma unroll
  for (int s = 0; s < NSPLIT; ++s) {
    const float* prow = part + ((size_t)s * NROWS + row) * PART_STRIDE;
    m[s] = prow[512 + h_o];
    l[s] = prow[520 + h_o];
  }
  float M = fmaxf(fmaxf(m[0], m[1]), fmaxf(m[2], m[3]));
  float L = 0.f, o0 = 0.f, o1 = 0.f;
#pragma unroll
  for (int s = 0; s < NSPLIT; ++s) {
    float fac = __expf(m[s] - M);
    L += l[s] * fac;
    const float* prow = part + ((size_t)s * NROWS + row) * PART_STRIDE;
    float2 o = *(const float2*)&prow[h_o * DHEAD + d0];
    o0 = fmaf(o.x, fac, o0);
    o1 = fmaf(o.y, fac, o1);
  }
  float inv = 1.0f / L;
  ao[(size_t)row * NDIM + h_o * DHEAD + d0] = o0 * inv;
  ao[(size_t)row * NDIM + h_o * DHEAD + d0 + 1] = o1 * inv;
}

// ---------------------------------------------------------------------------
extern "C" void kernel_launch(void* const* d_in, const int* in_sizes, int n_in,
                              void* d_out, int out_size, void* d_ws, size_t ws_size,
                              hipStream_t stream)
{
  (void)in_sizes; (void)n_in; (void)out_size; (void)ws_size;
  const float* x     = (const float*)d_in[0];
  const float* pos   = (const float*)d_in[1];
  const float* Wq    = (const float*)d_in[2];
  const float* Wk    = (const float*)d_in[3];
  const float* Wv    = (const float*)d_in[4];
  const float* Wo    = (const float*)d_in[5];
  const float* bo    = (const float*)d_in[6];
  const float* freqs = (const float*)d_in[7];

  float* ws = (float*)d_ws;
  float* qkv  = ws;                                   // [3][544][512]
  float* qb   = qkv;
  float* kb   = qkv + (size_t)NROWS * NDIM;
  float* vb   = qkv + (size_t)2 * NROWS * NDIM;
  float* ao   = qkv + (size_t)3 * NROWS * NDIM;       // [544][512]
  float* part = ao  + (size_t)NROWS * NDIM;           // [4][544][528]

  qkv_gemm_k<<<dim3((NROWS + 63) / 64, 24), 256, 0, stream>>>(x, Wq, Wk, Wv, qkv);
  attn_split_k<<<dim3(NROWS, NSPLIT), 256, 0, stream>>>(qb, kb, vb, pos, Wk, Wv, freqs, part);
  combine_k<<<dim3(NROWS), 256, 0, stream>>>(part, ao);
  out_gemm_k<<<dim3((NROWS + 63) / 64, 8), 256, 0, stream>>>(ao, Wo, bo, (float*)d_out);
}

// Round 8
// 167.278 us; speedup vs baseline: 1.4057x; 1.4057x over previous
//
#include <hip/hip_runtime.h>
#include <math.h>

#define NHEADS 8
#define DHEAD 64
#define NDIM 512
#define NFREQ 32
#define POSD 130           // 2*(32*2+1)
#define NB 2
#define NL 272
#define NLS 256
#define NROWS (NB*NL)      // 544
#define ATTN_SCALE 0.125f
#define PHYS_SCALE 51.5f
#define PI_F 3.14159265358979323846f
#define USTR 168           // u_s row stride (shorts): 16B-aligned, conflict-free
#define PSTR 72            // p_bf row stride (shorts)

typedef short s16x8 __attribute__((ext_vector_type(8)));
typedef float f32x4 __attribute__((ext_vector_type(4)));

__device__ __forceinline__ short bfb(float x) {
  unsigned short u = __builtin_bit_cast(unsigned short, (__bf16)x);
  return (short)u;
}

// ---------------------------------------------------------------------------
// K1: qkv = x @ [Wq | Wk[:512] | Wv[:512]]   (M=544, N=1536, K=512, fp32)
// ---------------------------------------------------------------------------
__global__ __launch_bounds__(256) void qkv_gemm_k(
    const float* __restrict__ x,
    const float* __restrict__ Wq, const float* __restrict__ Wk,
    const float* __restrict__ Wv,
    float* __restrict__ qkv)
{
  __shared__ float As[16][68];
  __shared__ float Bs[16][64];
  const int t  = threadIdx.x;
  const int m0 = blockIdx.x * 64;
  const int ng = blockIdx.y * 64;
  const int region = ng >> 9;
  const int n0 = ng & 511;
  const float* W = (region == 0) ? Wq : (region == 1) ? Wk : Wv;
  float* out = qkv + (size_t)region * (NROWS * NDIM);

  const int tx = t & 15, ty = t >> 4;
  const int arow = t >> 2, akq = (t & 3) * 4;
  const int brow = t >> 4, bcol = (t & 15) * 4;

  float acc[4][4];
#pragma unroll
  for (int i = 0; i < 4; ++i)
#pragma unroll
    for (int j = 0; j < 4; ++j) acc[i][j] = 0.f;

  for (int k0 = 0; k0 < 512; k0 += 16) {
    float4 av = make_float4(0.f, 0.f, 0.f, 0.f);
    if (m0 + arow < NROWS)
      av = *(const float4*)&x[(size_t)(m0 + arow) * NDIM + k0 + akq];
    As[akq + 0][arow] = av.x; As[akq + 1][arow] = av.y;
    As[akq + 2][arow] = av.z; As[akq + 3][arow] = av.w;
    *(float4*)&Bs[brow][bcol] =
        *(const float4*)&W[(size_t)(k0 + brow) * NDIM + n0 + bcol];
    __syncthreads();
#pragma unroll
    for (int kk = 0; kk < 16; ++kk) {
      float4 a = *(const float4*)&As[kk][ty * 4];
      float4 b = *(const float4*)&Bs[kk][tx * 4];
      float aa[4] = {a.x, a.y, a.z, a.w};
      float bb[4] = {b.x, b.y, b.z, b.w};
#pragma unroll
      for (int i = 0; i < 4; ++i)
#pragma unroll
        for (int j = 0; j < 4; ++j) acc[i][j] = fmaf(aa[i], bb[j], acc[i][j]);
    }
    __syncthreads();
  }
#pragma unroll
  for (int i = 0; i < 4; ++i) {
    int row = m0 + ty * 4 + i;
    if (row < NROWS)
      *(float4*)&out[(size_t)row * NDIM + n0 + tx * 4] =
          make_float4(acc[i][0], acc[i][1], acc[i][2], acc[i][3]);
  }
}

// ---------------------------------------------------------------------------
// K3: out = attn_out @ Wo + bo
// ---------------------------------------------------------------------------
__global__ __launch_bounds__(256) void out_gemm_k(
    const float* __restrict__ A, const float* __restrict__ Wo,
    const float* __restrict__ bo, float* __restrict__ out)
{
  __shared__ float As[16][68];
  __shared__ float Bs[16][64];
  const int t  = threadIdx.x;
  const int m0 = blockIdx.x * 64;
  const int n0 = blockIdx.y * 64;

  const int tx = t & 15, ty = t >> 4;
  const int arow = t >> 2, akq = (t & 3) * 4;
  const int brow = t >> 4, bcol = (t & 15) * 4;

  float acc[4][4];
#pragma unroll
  for (int i = 0; i < 4; ++i)
#pragma unroll
    for (int j = 0; j < 4; ++j) acc[i][j] = 0.f;

  for (int k0 = 0; k0 < 512; k0 += 16) {
    float4 av = make_float4(0.f, 0.f, 0.f, 0.f);
    if (m0 + arow < NROWS)
      av = *(const float4*)&A[(size_t)(m0 + arow) * NDIM + k0 + akq];
    As[akq + 0][arow] = av.x; As[akq + 1][arow] = av.y;
    As[akq + 2][arow] = av.z; As[akq + 3][arow] = av.w;
    *(float4*)&Bs[brow][bcol] =
        *(const float4*)&Wo[(size_t)(k0 + brow) * NDIM + n0 + bcol];
    __syncthreads();
#pragma unroll
    for (int kk = 0; kk < 16; ++kk) {
      float4 a = *(const float4*)&As[kk][ty * 4];
      float4 b = *(const float4*)&Bs[kk][tx * 4];
      float aa[4] = {a.x, a.y, a.z, a.w};
      float bb[4] = {b.x, b.y, b.z, b.w};
#pragma unroll
      for (int i = 0; i < 4; ++i)
#pragma unroll
        for (int j = 0; j < 4; ++j) acc[i][j] = fmaf(aa[i], bb[j], acc[i][j]);
    }
    __syncthreads();
  }
  float4 bv = *(const float4*)&bo[n0 + tx * 4];
  float bb[4] = {bv.x, bv.y, bv.z, bv.w};
#pragma unroll
  for (int i = 0; i < 4; ++i) {
    int row = m0 + ty * 4 + i;
    if (row < NROWS)
      *(float4*)&out[(size_t)row * NDIM + n0 + tx * 4] =
          make_float4(acc[i][0] + bb[0], acc[i][1] + bb[1],
                      acc[i][2] + bb[2], acc[i][3] + bb[3]);
  }
}

// ---------------------------------------------------------------------------
// K2: MFMA attention. One block (4 waves) per (b, query row).
// Permuted pe slot layout (applied to u, w, Wv_pe rows alike):
//   slot 0..31  = sin(rc*fr*pi)      (orig f = slot)
//   slot 32..63 = cos(rc*fr*pi)      (orig f = slot)
//   slot 64..95 = sin(th*fr*pi)      (orig f = slot+1)
//   slot 96..127= cos(th*fr*pi)      (orig f = slot+1)
//   slot 128 = rc (orig 64), slot 129 = th (orig 129), 130..159 = 0
// Fragment maps (gfx950, HW-verified): A m=lane&15 k=(lane>>4)*8+j;
// B n=lane&15 same k; D col=lane&15 row=(lane>>4)*4+reg.
// ---------------------------------------------------------------------------
__global__ __launch_bounds__(256) void attn_mfma_k(
    const float* __restrict__ qb, const float* __restrict__ kb,
    const float* __restrict__ vb, const float* __restrict__ pos,
    const float* __restrict__ Wk, const float* __restrict__ Wv,
    const float* __restrict__ freqs, float* __restrict__ attn_out)
{
  __shared__ float q_s[NDIM];
  __shared__ short u_s[16 * USTR];
  __shared__ short p_bf[16 * PSTR];
  __shared__ float p_s[NHEADS][64];
  __shared__ float s_l[NHEADS][64];
  __shared__ float w_s[NHEADS][160];
  __shared__ float rc_s[64], th_s[64];
  __shared__ float frp_s[NFREQ];
  __shared__ float m_s[NHEADS], l_s[NHEADS], fac_s[NHEADS];

  const int row = blockIdx.x;
  const int b = row / NL;
  const int i = row - b * NL;
  const bool spatial = (i < NLS);
  const int t = threadIdx.x;
  const int lane = t & 63;
  const int wv = t >> 6;            // wave 0..3
  const int g = lane >> 4;          // lane-group 0..3
  const int lr = lane & 15;

  for (int idx = t; idx < 16 * USTR / 2; idx += 256) ((int*)u_s)[idx] = 0;
  for (int idx = t; idx < 16 * PSTR / 2; idx += 256) ((int*)p_bf)[idx] = 0;
  if (t < NFREQ) frp_s[t] = freqs[t] * PI_F;
  {
    float2 qv = *(const float2*)&qb[(size_t)row * NDIM + t * 2];
    q_s[t * 2] = qv.x; q_s[t * 2 + 1] = qv.y;
  }
  if (t < NHEADS) { m_s[t] = -1e30f; l_s[t] = 0.f; }
  __syncthreads();

  // u[h][slot] = sum_d q[h*64+d] * Wk[512+f(slot)][h*64+d]  (bf16, permuted)
  if (spatial) {
    for (int idx = t; idx < NHEADS * POSD; idx += 256) {
      int h = idx / POSD, f = idx - h * POSD;
      const float* wr = &Wk[(size_t)(512 + f) * NDIM + h * DHEAD];
      const float* qs = &q_s[h * DHEAD];
      float a0 = 0.f, a1 = 0.f;
#pragma unroll
      for (int d = 0; d < 64; d += 8) {
        float4 w0 = *(const float4*)&wr[d];
        float4 w1 = *(const float4*)&wr[d + 4];
        a0 = fmaf(qs[d], w0.x, a0);     a0 = fmaf(qs[d + 1], w0.y, a0);
        a0 = fmaf(qs[d + 2], w0.z, a0); a0 = fmaf(qs[d + 3], w0.w, a0);
        a1 = fmaf(qs[d + 4], w1.x, a1); a1 = fmaf(qs[d + 5], w1.y, a1);
        a1 = fmaf(qs[d + 6], w1.z, a1); a1 = fmaf(qs[d + 7], w1.w, a1);
      }
      int slot = (f < 64) ? f : (f == 64) ? 128 : (f == 129) ? 129 : f - 1;
      u_s[h * USTR + slot] = bfb(a0 + a1);
    }
  }

  float px = 0.f, py = 0.f;
  if (spatial) {
    float2 pv = *(const float2*)&pos[(size_t)(b * NLS + i) * 2];
    px = pv.x; py = pv.y;
  }

  const int h_o = t >> 5;
  const int d0 = (t & 31) * 2;
  float out0 = 0.f, out1 = 0.f;
  f32x4 wacc[3];
#pragma unroll
  for (int q = 0; q < 3; ++q) wacc[q] = (f32x4){0.f, 0.f, 0.f, 0.f};

  for (int tile = 0; tile < 5; ++tile) {
    const int tn = (tile < 4) ? 64 : 16;
    const int kbase = tile * 64;
    const bool pe_act = spatial && (tile < 4);

    __syncthreads();

    // ---- P1: rc/th + QK logits (fp32) ----
    if (pe_act && t < 64) {
      float2 kp = *(const float2*)&pos[(size_t)(b * NLS + kbase + t) * 2];
      float dx = kp.x - px, dy = kp.y - py;
      float r = sqrtf(dx * dx + dy * dy + 1e-8f);
      rc_s[t] = r / (PHYS_SCALE + r);
      th_s[t] = atan2f(dy, dx) * (1.0f / PI_F);
    }
    {
      const int h = t >> 5, jj = t & 31;
      const float* qs = &q_s[h * DHEAD];
#pragma unroll
      for (int rep = 0; rep < 2; ++rep) {
        int j = jj + rep * 32;
        if (j < tn) {
          const float* kr = &kb[(size_t)(b * NL + kbase + j) * NDIM + h * DHEAD];
          float a0 = 0.f, a1 = 0.f;
#pragma unroll
          for (int d = 0; d < 64; d += 8) {
            float4 k0v = *(const float4*)&kr[d];
            float4 k1v = *(const float4*)&kr[d + 4];
            a0 = fmaf(qs[d], k0v.x, a0);     a0 = fmaf(qs[d + 1], k0v.y, a0);
            a0 = fmaf(qs[d + 2], k0v.z, a0); a0 = fmaf(qs[d + 3], k0v.w, a0);
            a1 = fmaf(qs[d + 4], k1v.x, a1); a1 = fmaf(qs[d + 5], k1v.y, a1);
            a1 = fmaf(qs[d + 6], k1v.z, a1); a1 = fmaf(qs[d + 7], k1v.w, a1);
          }
          s_l[h][j] = (a0 + a1) * ATTN_SCALE;
        }
      }
    }
    __syncthreads();

    // ---- P2: logits_pe via MFMA; wave wv owns keys kbase+wv*16..+15 ----
    if (pe_act) {
      const int keyloc = wv * 16 + lr;
      const float rc = rc_s[keyloc], th = th_s[keyloc];
      const float* frp = &frp_s[g * 8];
      s16x8 a0, a1, a2, a3, a4;
#pragma unroll
      for (int j = 0; j < 8; ++j) {
        float s1, c1, s2, c2;
        __sincosf(rc * frp[j], &s1, &c1);
        __sincosf(th * frp[j], &s2, &c2);
        a0[j] = bfb(s1); a1[j] = bfb(c1); a2[j] = bfb(s2); a3[j] = bfb(c2);
        a4[j] = 0;
      }
      if (g == 0) { a4[0] = bfb(rc); a4[1] = bfb(th); }
      const short* ur = &u_s[lr * USTR + g * 8];
      f32x4 acc = (f32x4){0.f, 0.f, 0.f, 0.f};
      acc = __builtin_amdgcn_mfma_f32_16x16x32_bf16(a0, *(const s16x8*)(ur), acc, 0, 0, 0);
      acc = __builtin_amdgcn_mfma_f32_16x16x32_bf16(a1, *(const s16x8*)(ur + 32), acc, 0, 0, 0);
      acc = __builtin_amdgcn_mfma_f32_16x16x32_bf16(a2, *(const s16x8*)(ur + 64), acc, 0, 0, 0);
      acc = __builtin_amdgcn_mfma_f32_16x16x32_bf16(a3, *(const s16x8*)(ur + 96), acc, 0, 0, 0);
      acc = __builtin_amdgcn_mfma_f32_16x16x32_bf16(a4, *(const s16x8*)(ur + 128), acc, 0, 0, 0);
      if (lr < NHEADS) {
#pragma unroll
        for (int r = 0; r < 4; ++r)
          s_l[lr][wv * 16 + g * 4 + r] += acc[r] * ATTN_SCALE;
      }
    }
    __syncthreads();

    // ---- P3: online softmax (32 lanes per head) ----
    {
      const int h = t >> 5, ln = t & 31;
      float v0 = (ln < tn) ? s_l[h][ln] : -1e30f;
      float v1 = (ln + 32 < tn) ? s_l[h][ln + 32] : -1e30f;
      float mx = fmaxf(v0, v1);
#pragma unroll
      for (int off = 16; off > 0; off >>= 1)
        mx = fmaxf(mx, __shfl_xor(mx, off, 32));
      float m_old = m_s[h];
      float m_new = fmaxf(m_old, mx);
      float p0 = (ln < tn) ? __expf(v0 - m_new) : 0.f;
      float p1 = (ln + 32 < tn) ? __expf(v1 - m_new) : 0.f;
      p_s[h][ln] = p0;        p_bf[h * PSTR + ln] = bfb(p0);
      p_s[h][ln + 32] = p1;   p_bf[h * PSTR + ln + 32] = bfb(p1);
      float sum = p0 + p1;
#pragma unroll
      for (int off = 16; off > 0; off >>= 1)
        sum += __shfl_xor(sum, off, 32);
      if (ln == 0) {
        float fac = __expf(m_old - m_new);
        m_s[h] = m_new;
        l_s[h] = l_s[h] * fac + sum;
        fac_s[h] = fac;
      }
    }
    __syncthreads();

    // ---- P4: PV (fp32) ----
    {
      float fac = fac_s[h_o];
      out0 *= fac; out1 *= fac;
      const float* vbase = &vb[(size_t)(b * NL + kbase) * NDIM + h_o * DHEAD + d0];
      const float* pp = p_s[h_o];
      for (int j4 = 0; j4 < tn; j4 += 4) {
        float4 p4 = *(const float4*)&pp[j4];
        float2 v0v = *(const float2*)&vbase[(size_t)(j4 + 0) * NDIM];
        float2 v1v = *(const float2*)&vbase[(size_t)(j4 + 1) * NDIM];
        float2 v2v = *(const float2*)&vbase[(size_t)(j4 + 2) * NDIM];
        float2 v3v = *(const float2*)&vbase[(size_t)(j4 + 3) * NDIM];
        out0 = fmaf(p4.x, v0v.x, out0); out1 = fmaf(p4.x, v0v.y, out1);
        out0 = fmaf(p4.y, v1v.x, out0); out1 = fmaf(p4.y, v1v.y, out1);
        out0 = fmaf(p4.z, v2v.x, out0); out1 = fmaf(p4.z, v2v.y, out1);
        out0 = fmaf(p4.w, v3v.x, out0); out1 = fmaf(p4.w, v3v.y, out1);
      }
    }

    // ---- P5: w accumulation via MFMA (pe^T[slot x key] @ p[key x head]) ----
    if (spatial) {
      const float facw = fac_s[lr & 7];
#pragma unroll
      for (int q = 0; q < 3; ++q) {
        const int mc = wv + q * 4;
        if (mc < 10) {
#pragma unroll
          for (int r = 0; r < 4; ++r) wacc[q][r] *= facw;
          if (tile < 4) {
            const int s = mc * 16 + lr;            // slot, 0..159
            const float Fp = frp_s[s & 31];
            const bool useTh = (s >= 64 && s < 128) || (s == 129);
            const bool useCos = (s & 32) != 0;
#pragma unroll
            for (int kc = 0; kc < 2; ++kc) {
              s16x8 a;
#pragma unroll
              for (int jj = 0; jj < 8; ++jj) {
                const int j = kc * 32 + g * 8 + jj;
                float x = useTh ? th_s[j] : rc_s[j];
                float v;
                if (s < 128) {
                  float sn, cs;
                  __sincosf(x * Fp, &sn, &cs);
                  v = useCos ? cs : sn;
                } else {
                  v = (s < 130) ? x : 0.f;
                }
                a[jj] = bfb(v);
              }
              const s16x8 pb = *(const s16x8*)&p_bf[lr * PSTR + kc * 32 + g * 8];
              wacc[q] = __builtin_amdgcn_mfma_f32_16x16x32_bf16(a, pb, wacc[q], 0, 0, 0);
            }
          }
        }
      }
    }
  }

  // ---- epilogue: gather w, project with Wv_pe (permuted rows) ----
  __syncthreads();
  if (spatial && lr < NHEADS) {
#pragma unroll
    for (int q = 0; q < 3; ++q) {
      const int mc = wv + q * 4;
      if (mc < 10) {
#pragma unroll
        for (int r = 0; r < 4; ++r)
          w_s[lr][mc * 16 + g * 4 + r] = wacc[q][r];
      }
    }
  }
  __syncthreads();

  float invl = 1.0f / l_s[h_o];
  if (spatial) {
    const float* wsr = w_s[h_o];
    const float* wvb = &Wv[(size_t)512 * NDIM + h_o * DHEAD + d0];
#pragma unroll 4
    for (int sf = 0; sf < 64; sf += 4) {      // slots 0..63 -> orig rows sf..
      float4 w4 = *(const float4*)&wsr[sf];
      float2 r0 = *(const float2*)&wvb[(size_t)(sf + 0) * NDIM];
      float2 r1 = *(const float2*)&wvb[(size_t)(sf + 1) * NDIM];
      float2 r2 = *(const float2*)&wvb[(size_t)(sf + 2) * NDIM];
      float2 r3 = *(const float2*)&wvb[(size_t)(sf + 3) * NDIM];
      out0 = fmaf(w4.x, r0.x, out0); out1 = fmaf(w4.x, r0.y, out1);
      out0 = fmaf(w4.y, r1.x, out0); out1 = fmaf(w4.y, r1.y, out1);
      out0 = fmaf(w4.z, r2.x, out0); out1 = fmaf(w4.z, r2.y, out1);
      out0 = fmaf(w4.w, r3.x, out0); out1 = fmaf(w4.w, r3.y, out1);
    }
#pragma unroll 4
    for (int sf = 64; sf < 128; sf += 4) {    // slots 64..127 -> rows sf+1..
      float4 w4 = *(const float4*)&wsr[sf];
      float2 r0 = *(const float2*)&wvb[(size_t)(sf + 1) * NDIM];
      float2 r1 = *(const float2*)&wvb[(size_t)(sf + 2) * NDIM];
      float2 r2 = *(const float2*)&wvb[(size_t)(sf + 3) * NDIM];
      float2 r3 = *(const float2*)&wvb[(size_t)(sf + 4) * NDIM];
      out0 = fmaf(w4.x, r0.x, out0); out1 = fmaf(w4.x, r0.y, out1);
      out0 = fmaf(w4.y, r1.x, out0); out1 = fmaf(w4.y, r1.y, out1);
      out0 = fmaf(w4.z, r2.x, out0); out1 = fmaf(w4.z, r2.y, out1);
      out0 = fmaf(w4.w, r3.x, out0); out1 = fmaf(w4.w, r3.y, out1);
    }
    {
      float2 rrc = *(const float2*)&wvb[(size_t)64 * NDIM];    // slot128 = rc
      float2 rth = *(const float2*)&wvb[(size_t)129 * NDIM];   // slot129 = th
      out0 = fmaf(wsr[128], rrc.x, out0); out1 = fmaf(wsr[128], rrc.y, out1);
      out0 = fmaf(wsr[129], rth.x, out0); out1 = fmaf(wsr[129], rth.y, out1);
    }
  }
  attn_out[(size_t)row * NDIM + h_o * DHEAD + d0] = out0 * invl;
  attn_out[(size_t)row * NDIM + h_o * DHEAD + d0 + 1] = out1 * invl;
}

// ---------------------------------------------------------------------------
extern "C" void kernel_launch(void* const* d_in, const int* in_sizes, int n_in,
                              void* d_out, int out_size, void* d_ws, size_t ws_size,
                              hipStream_t stream)
{
  (void)in_sizes; (void)n_in; (void)out_size; (void)ws_size;
  const float* x     = (const float*)d_in[0];
  const float* pos   = (const float*)d_in[1];
  const float* Wq    = (const float*)d_in[2];
  const float* Wk    = (const float*)d_in[3];
  const float* Wv    = (const float*)d_in[4];
  const float* Wo    = (const float*)d_in[5];
  const float* bo    = (const float*)d_in[6];
  const float* freqs = (const float*)d_in[7];

  float* ws = (float*)d_ws;
  float* qkv = ws;                                   // [3][544][512]
  float* qb  = qkv;
  float* kb  = qkv + (size_t)NROWS * NDIM;
  float* vb  = qkv + (size_t)2 * NROWS * NDIM;
  float* ao  = qkv + (size_t)3 * NROWS * NDIM;       // [544][512]

  qkv_gemm_k<<<dim3((NROWS + 63) / 64, 24), 256, 0, stream>>>(x, Wq, Wk, Wv, qkv);
  attn_mfma_k<<<dim3(NROWS), 256, 0, stream>>>(qb, kb, vb, pos, Wk, Wv, freqs, ao);
  out_gemm_k<<<dim3((NROWS + 63) / 64, 8), 256, 0, stream>>>(ao, Wo, bo, (float*)d_out);
}